// Round 1
// baseline (242.886 us; speedup 1.0000x reference)
//
#include <hip/hip_runtime.h>
#include <hip/hip_bf16.h>
#include <cstdint>
#include <cstddef>

// Problem constants
#define BS_TOT 12288   // 3 * 4096 rows
#define DIM    256     // embedding dim
#define BATCH_ 4096
#define NTILE  96      // BS_TOT / 128

typedef _Float16 f16x8 __attribute__((ext_vector_type(8)));
typedef _Float16 f16x4 __attribute__((ext_vector_type(4)));
typedef float    f32x4 __attribute__((ext_vector_type(4)));

#define AS1 __attribute__((address_space(1)))
#define AS3 __attribute__((address_space(3)))

// ---------------------------------------------------------------------------
// Kernel 1: row-normalize. One wave per row (4 rows / 256-thread block).
// Writes f16 normalized rows (for MFMA) + fp32 inverse norms (for exact
// numerator path).
// ---------------------------------------------------------------------------
__global__ __launch_bounds__(256) void normalize_kernel(const float* __restrict__ x,
                                                        _Float16* __restrict__ xn,
                                                        float* __restrict__ invn) {
  const int wave = threadIdx.x >> 6;
  const int lane = threadIdx.x & 63;
  const int row  = blockIdx.x * 4 + wave;
  const float4 v = ((const float4*)(x + (size_t)row * DIM))[lane];
  float ss = v.x*v.x + v.y*v.y + v.z*v.z + v.w*v.w;
  #pragma unroll
  for (int off = 1; off < 64; off <<= 1) ss += __shfl_xor(ss, off, 64);
  const float s = 1.0f / fmaxf(sqrtf(ss), 1e-6f);
  if (lane == 0) invn[row] = s;
  f16x4 h;
  h.x = (_Float16)(v.x * s); h.y = (_Float16)(v.y * s);
  h.z = (_Float16)(v.z * s); h.w = (_Float16)(v.w * s);
  ((f16x4*)(xn + (size_t)row * DIM))[lane] = h;
}

// ---------------------------------------------------------------------------
// Kernel 2: tiled A@A^T with fused exp + masked row-sum (den).
// 128x128 tile per 256-thread block; 4 waves in 2x2; each wave 64x64 via
// 4x4 of 16x16x32 f16 MFMA. m97-style staging: global_load_lds width 16,
// LDS [row][32] f16, ds_read_b128 fragments.
// Mask: column excluded for row iff (gc % 4) == (gr % 4). With 16-aligned
// bases: gr%4 == acc reg index r, gc%4 == (lane&15)&3 -> tile-invariant.
// ---------------------------------------------------------------------------
__global__ __launch_bounds__(256) void gemm_den_kernel(const _Float16* __restrict__ xn,
                                                       float* __restrict__ den) {
  __shared__ _Float16 As[128 * 32];
  __shared__ _Float16 Bs[128 * 32];

  const int tid  = threadIdx.x;
  const int tJ   = blockIdx.x;   // column tile
  const int tI   = blockIdx.y;   // row tile
  const int wave = tid >> 6, lane = tid & 63;
  const int wr   = wave >> 1, wc = wave & 1;
  const int quad = lane >> 4, c16 = lane & 15;

  f32x4 acc[4][4] = {};

  const _Float16* Ab = xn + (size_t)tI * 128 * DIM;
  const _Float16* Bb = xn + (size_t)tJ * 128 * DIM;

  // staging map: thread handles two 16B chunks (8 f16 each).
  const int r0 = tid >> 2,      c0 = (tid & 3) * 8;
  const int g1 = tid + 256;
  const int r1 = g1 >> 2,       c1 = (g1 & 3) * 8;

  for (int k0 = 0; k0 < DIM; k0 += 32) {
    __builtin_amdgcn_global_load_lds((AS1 void*)(Ab + (size_t)r0 * DIM + k0 + c0),
                                     (AS3 void*)(As + tid * 8), 16, 0, 0);
    __builtin_amdgcn_global_load_lds((AS1 void*)(Ab + (size_t)r1 * DIM + k0 + c1),
                                     (AS3 void*)(As + g1 * 8), 16, 0, 0);
    __builtin_amdgcn_global_load_lds((AS1 void*)(Bb + (size_t)r0 * DIM + k0 + c0),
                                     (AS3 void*)(Bs + tid * 8), 16, 0, 0);
    __builtin_amdgcn_global_load_lds((AS1 void*)(Bb + (size_t)r1 * DIM + k0 + c1),
                                     (AS3 void*)(Bs + g1 * 8), 16, 0, 0);
    __syncthreads();   // drains vmcnt(0) before barrier (compiler-inserted)

    f16x8 af[4], bf[4];
    #pragma unroll
    for (int mi = 0; mi < 4; mi++)
      af[mi] = *(const f16x8*)(As + (wr*64 + mi*16 + c16) * 32 + quad*8);
    #pragma unroll
    for (int ni = 0; ni < 4; ni++)
      bf[ni] = *(const f16x8*)(Bs + (wc*64 + ni*16 + c16) * 32 + quad*8);

    #pragma unroll
    for (int mi = 0; mi < 4; mi++)
      #pragma unroll
      for (int ni = 0; ni < 4; ni++)
        acc[mi][ni] = __builtin_amdgcn_mfma_f32_16x16x32_f16(af[mi], bf[ni], acc[mi][ni], 0, 0, 0);
    __syncthreads();
  }

  // Epilogue: E = exp(S * 10); masked row-sums -> den.
  // C/D layout (verified m89/m91): col = lane&15, row = quad*4 + reg.
  const int rowBase = tI*128 + wr*64;
  #pragma unroll
  for (int mi = 0; mi < 4; mi++) {
    const int grb = rowBase + mi*16 + quad*4;
    #pragma unroll
    for (int r = 0; r < 4; r++) {
      float s = 0.0f;
      if ((c16 & 3) != r) {          // include iff col%4 != row%4
        #pragma unroll
        for (int ni = 0; ni < 4; ni++)
          s += __expf(acc[mi][ni][r] * 10.0f);
      }
      #pragma unroll
      for (int off = 1; off < 16; off <<= 1) s += __shfl_xor(s, off, 64);
      if (c16 == 0) atomicAdd(&den[grb + r], s);
    }
  }
}

// ---------------------------------------------------------------------------
// Kernel 3: numerators (fp32, exact path) + final loss. One wave per p,
// 4 p per block, one atomicAdd per block into d_out[0].
// pair(a,b,n)= -log(n/(n+den_a)) - log(n/(n+den_b))
//           = log(n+den_a) + log(n+den_b) - 2*z   with n = exp(z)
// ---------------------------------------------------------------------------
__global__ __launch_bounds__(256) void loss_kernel(const float* __restrict__ x,
                                                   const float* __restrict__ invn,
                                                   const float* __restrict__ den,
                                                   float* __restrict__ out) {
  __shared__ float part[4];
  const int wave = threadIdx.x >> 6, lane = threadIdx.x & 63;
  const int p = blockIdx.x * 4 + wave;
  const float4 a = ((const float4*)(x + (size_t)p * DIM))[lane];
  const float4 b = ((const float4*)(x + (size_t)(BATCH_ + p) * DIM))[lane];
  const float4 c = ((const float4*)(x + (size_t)(2*BATCH_ + p) * DIM))[lane];
  float d12 = a.x*b.x + a.y*b.y + a.z*b.z + a.w*b.w;
  float d13 = a.x*c.x + a.y*c.y + a.z*c.z + a.w*c.w;
  float d23 = b.x*c.x + b.y*c.y + b.z*c.z + b.w*c.w;
  #pragma unroll
  for (int off = 1; off < 64; off <<= 1) {
    d12 += __shfl_xor(d12, off, 64);
    d13 += __shfl_xor(d13, off, 64);
    d23 += __shfl_xor(d23, off, 64);
  }
  if (lane == 0) {
    const float s1 = invn[p], s2 = invn[BATCH_ + p], s3 = invn[2*BATCH_ + p];
    const float z12 = d12 * s1 * s2 * 10.0f;
    const float z13 = d13 * s1 * s3 * 10.0f;
    const float z23 = d23 * s2 * s3 * 10.0f;
    const float n12 = __expf(z12), n13 = __expf(z13), n23 = __expf(z23);
    const float e1 = den[p], e2 = den[BATCH_ + p], e3 = den[2*BATCH_ + p];
    part[wave] = logf(n12 + e1) + logf(n12 + e2) - 2.0f * z12
               + logf(n13 + e1) + logf(n13 + e3) - 2.0f * z13
               + logf(n23 + e2) + logf(n23 + e3) - 2.0f * z23;
  }
  __syncthreads();
  if (threadIdx.x == 0) {
    atomicAdd(out, (part[0] + part[1] + part[2] + part[3]) * (1.0f / (2.0f * BATCH_)));
  }
}

// ---------------------------------------------------------------------------
extern "C" void kernel_launch(void* const* d_in, const int* in_sizes, int n_in,
                              void* d_out, int out_size, void* d_ws, size_t ws_size,
                              hipStream_t stream) {
  const float* x = (const float*)d_in[0];
  float* out = (float*)d_out;

  // workspace layout
  char* ws = (char*)d_ws;
  _Float16* xn  = (_Float16*)ws;                                 // 12288*256*2 = 6291456 B
  float*    invn = (float*)(ws + (size_t)BS_TOT * DIM * 2);      // 49152 B
  float*    den  = (float*)(ws + (size_t)BS_TOT * DIM * 2 + BS_TOT * 4); // 49152 B

  hipMemsetAsync(den, 0, BS_TOT * sizeof(float), stream);
  hipMemsetAsync(d_out, 0, out_size * sizeof(float), stream);

  normalize_kernel<<<BS_TOT / 4, 256, 0, stream>>>(x, xn, invn);
  gemm_den_kernel<<<dim3(NTILE, NTILE), 256, 0, stream>>>(xn, den);
  loss_kernel<<<BATCH_ / 4, 256, 0, stream>>>(x, invn, den, out);
}

// Round 2
// 153.822 us; speedup vs baseline: 1.5790x; 1.5790x over previous
//
#include <hip/hip_runtime.h>
#include <hip/hip_bf16.h>
#include <cstdint>
#include <cstddef>

// Problem constants
#define BS_TOT 12288   // 3 * 4096 rows
#define DIM    256     // embedding dim
#define BATCH_ 4096
#define NTILE  96      // BS_TOT / 128
#define NPAIR  4656    // NTILE*(NTILE+1)/2 — upper-triangular tile pairs

typedef _Float16 f16x8 __attribute__((ext_vector_type(8)));
typedef _Float16 f16x4 __attribute__((ext_vector_type(4)));
typedef float    f32x4 __attribute__((ext_vector_type(4)));

#define AS1 __attribute__((address_space(1)))
#define AS3 __attribute__((address_space(3)))

// ---------------------------------------------------------------------------
// Kernel 1: row-normalize. One wave per row (4 rows / 256-thread block).
// ---------------------------------------------------------------------------
__global__ __launch_bounds__(256) void normalize_kernel(const float* __restrict__ x,
                                                        _Float16* __restrict__ xn,
                                                        float* __restrict__ invn) {
  const int wave = threadIdx.x >> 6;
  const int lane = threadIdx.x & 63;
  const int row  = blockIdx.x * 4 + wave;
  const float4 v = ((const float4*)(x + (size_t)row * DIM))[lane];
  float ss = v.x*v.x + v.y*v.y + v.z*v.z + v.w*v.w;
  #pragma unroll
  for (int off = 1; off < 64; off <<= 1) ss += __shfl_xor(ss, off, 64);
  const float s = 1.0f / fmaxf(sqrtf(ss), 1e-6f);
  if (lane == 0) invn[row] = s;
  f16x4 h;
  h.x = (_Float16)(v.x * s); h.y = (_Float16)(v.y * s);
  h.z = (_Float16)(v.z * s); h.w = (_Float16)(v.w * s);
  ((f16x4*)(xn + (size_t)row * DIM))[lane] = h;
}

// ---------------------------------------------------------------------------
// Kernel 2: symmetric tiled A@A^T with fused exp + masked row/col sums.
// Upper-triangular tile pairs only (E and the mod-4 mask are both symmetric):
//   tI <  tJ : add masked row-sums to den[rows] AND masked col-sums to den[cols]
//   tI == tJ : row-sums only (full 128x128 tile; diagonal is masked out anyway
//              since k%4 == k%4)
// 128x128 tile / block; BK=64 as two 32-wide sub-buffers (keeps the [128][32]
// bank-friendly layout) -> 4 K-iterations, half the barriers of BK=32.
// Mask: exclude iff col%4 == row%4; with 16-aligned bases this is
// (c16&3) == acc-reg-index r (tile-invariant).
// ---------------------------------------------------------------------------
__global__ __launch_bounds__(256) void gemm_den_kernel(const _Float16* __restrict__ xn,
                                                       float* __restrict__ den) {
  __shared__ _Float16 As[2][128 * 32];
  __shared__ _Float16 Bs[2][128 * 32];

  const int tid = threadIdx.x;

  // triangular decode: blockIdx.x -> (tI <= tJ)
  const int t = blockIdx.x;
  int j = (int)((sqrtf(8.0f * (float)t + 1.0f) - 1.0f) * 0.5f);
  while ((j + 1) * (j + 2) / 2 <= t) j++;
  while (j * (j + 1) / 2 > t) j--;
  const int tI = t - j * (j + 1) / 2;   // 0..j
  const int tJ = j;

  const int wave = tid >> 6, lane = tid & 63;
  const int wr   = wave >> 1, wc = wave & 1;
  const int quad = lane >> 4, c16 = lane & 15;

  f32x4 acc[4][4] = {};

  const _Float16* Ab = xn + (size_t)tI * 128 * DIM;
  const _Float16* Bb = xn + (size_t)tJ * 128 * DIM;

  // staging map: per sub-buffer, thread handles two 16B chunks (8 f16 each)
  const int r0 = tid >> 2,  c0 = (tid & 3) * 8;
  const int g1 = tid + 256;
  const int r1 = g1 >> 2,   c1 = (g1 & 3) * 8;

  for (int k0 = 0; k0 < DIM; k0 += 64) {
    #pragma unroll
    for (int b = 0; b < 2; b++) {
      const int kb = k0 + b * 32;
      __builtin_amdgcn_global_load_lds((AS1 void*)(Ab + (size_t)r0 * DIM + kb + c0),
                                       (AS3 void*)(As[b] + tid * 8), 16, 0, 0);
      __builtin_amdgcn_global_load_lds((AS1 void*)(Ab + (size_t)r1 * DIM + kb + c1),
                                       (AS3 void*)(As[b] + g1 * 8), 16, 0, 0);
      __builtin_amdgcn_global_load_lds((AS1 void*)(Bb + (size_t)r0 * DIM + kb + c0),
                                       (AS3 void*)(Bs[b] + tid * 8), 16, 0, 0);
      __builtin_amdgcn_global_load_lds((AS1 void*)(Bb + (size_t)r1 * DIM + kb + c1),
                                       (AS3 void*)(Bs[b] + g1 * 8), 16, 0, 0);
    }
    __syncthreads();

    #pragma unroll
    for (int b = 0; b < 2; b++) {
      f16x8 af[4], bf[4];
      #pragma unroll
      for (int mi = 0; mi < 4; mi++)
        af[mi] = *(const f16x8*)(As[b] + (wr*64 + mi*16 + c16) * 32 + quad*8);
      #pragma unroll
      for (int ni = 0; ni < 4; ni++)
        bf[ni] = *(const f16x8*)(Bs[b] + (wc*64 + ni*16 + c16) * 32 + quad*8);

      #pragma unroll
      for (int mi = 0; mi < 4; mi++)
        #pragma unroll
        for (int ni = 0; ni < 4; ni++)
          acc[mi][ni] = __builtin_amdgcn_mfma_f32_16x16x32_f16(af[mi], bf[ni], acc[mi][ni], 0, 0, 0);
    }
    __syncthreads();
  }

  // Epilogue. C/D layout (m89/m91): col = c16, row = quad*4 + r.
  const int rowBase = tI * 128 + wr * 64;
  const int colBase = tJ * 128 + wc * 64;
  float colsum[4] = {0.f, 0.f, 0.f, 0.f};

  #pragma unroll
  for (int mi = 0; mi < 4; mi++) {
    #pragma unroll
    for (int r = 0; r < 4; r++) {
      float rs = 0.0f;
      if ((c16 & 3) != r) {            // include iff col%4 != row%4
        #pragma unroll
        for (int ni = 0; ni < 4; ni++) {
          const float e = __expf(acc[mi][ni][r] * 10.0f);
          rs += e;
          colsum[ni] += e;
        }
      }
      #pragma unroll
      for (int off = 1; off < 16; off <<= 1) rs += __shfl_xor(rs, off, 64);
      if (c16 == 0) atomicAdd(&den[rowBase + mi*16 + quad*4 + r], rs);
    }
  }

  if (tI != tJ) {                      // off-diagonal: scatter column sums too
    #pragma unroll
    for (int ni = 0; ni < 4; ni++) {
      float cs = colsum[ni];
      cs += __shfl_xor(cs, 16, 64);
      cs += __shfl_xor(cs, 32, 64);
      if (quad == 0) atomicAdd(&den[colBase + ni*16 + c16], cs);
    }
  }
}

// ---------------------------------------------------------------------------
// Kernel 3: numerators (fp32, exact path) + final loss.
// ---------------------------------------------------------------------------
__global__ __launch_bounds__(256) void loss_kernel(const float* __restrict__ x,
                                                   const float* __restrict__ invn,
                                                   const float* __restrict__ den,
                                                   float* __restrict__ out) {
  __shared__ float part[4];
  const int wave = threadIdx.x >> 6, lane = threadIdx.x & 63;
  const int p = blockIdx.x * 4 + wave;
  const float4 a = ((const float4*)(x + (size_t)p * DIM))[lane];
  const float4 b = ((const float4*)(x + (size_t)(BATCH_ + p) * DIM))[lane];
  const float4 c = ((const float4*)(x + (size_t)(2*BATCH_ + p) * DIM))[lane];
  float d12 = a.x*b.x + a.y*b.y + a.z*b.z + a.w*b.w;
  float d13 = a.x*c.x + a.y*c.y + a.z*c.z + a.w*c.w;
  float d23 = b.x*c.x + b.y*c.y + b.z*c.z + b.w*c.w;
  #pragma unroll
  for (int off = 1; off < 64; off <<= 1) {
    d12 += __shfl_xor(d12, off, 64);
    d13 += __shfl_xor(d13, off, 64);
    d23 += __shfl_xor(d23, off, 64);
  }
  if (lane == 0) {
    const float s1 = invn[p], s2 = invn[BATCH_ + p], s3 = invn[2*BATCH_ + p];
    const float z12 = d12 * s1 * s2 * 10.0f;
    const float z13 = d13 * s1 * s3 * 10.0f;
    const float z23 = d23 * s2 * s3 * 10.0f;
    const float n12 = __expf(z12), n13 = __expf(z13), n23 = __expf(z23);
    const float e1 = den[p], e2 = den[BATCH_ + p], e3 = den[2*BATCH_ + p];
    part[wave] = logf(n12 + e1) + logf(n12 + e2) - 2.0f * z12
               + logf(n13 + e1) + logf(n13 + e3) - 2.0f * z13
               + logf(n23 + e2) + logf(n23 + e3) - 2.0f * z23;
  }
  __syncthreads();
  if (threadIdx.x == 0) {
    atomicAdd(out, (part[0] + part[1] + part[2] + part[3]) * (1.0f / (2.0f * BATCH_)));
  }
}

// ---------------------------------------------------------------------------
extern "C" void kernel_launch(void* const* d_in, const int* in_sizes, int n_in,
                              void* d_out, int out_size, void* d_ws, size_t ws_size,
                              hipStream_t stream) {
  const float* x = (const float*)d_in[0];
  float* out = (float*)d_out;

  char* ws = (char*)d_ws;
  _Float16* xn   = (_Float16*)ws;                                        // 6 MB
  float*    invn = (float*)(ws + (size_t)BS_TOT * DIM * 2);              // 48 KB
  float*    den  = (float*)(ws + (size_t)BS_TOT * DIM * 2 + BS_TOT * 4); // 48 KB

  hipMemsetAsync(den, 0, BS_TOT * sizeof(float), stream);
  hipMemsetAsync(d_out, 0, out_size * sizeof(float), stream);

  normalize_kernel<<<BS_TOT / 4, 256, 0, stream>>>(x, xn, invn);
  gemm_den_kernel<<<NPAIR, 256, 0, stream>>>(xn, den);
  loss_kernel<<<BATCH_ / 4, 256, 0, stream>>>(x, invn, den, out);
}